// Round 22
// baseline (466.553 us; speedup 1.0000x reference)
//
#include <hip/hip_runtime.h>
#include <hip/hip_bf16.h>
#include <math.h>

// MixtralMoE: B=1, S=4096, H=1024, E=8, F=3584, K=2
// inputs: hidden_states, gate_w, w1, w3, w2 (all fp32); output fp32 [4096,1024]

#define T_TOK 4096
#define H_DIM 1024
#define E_NUM 8
#define F_DIM 3584
#define KSPL 1792           // ffn2 split-K chunk (2 chunks of 28 K-steps)

typedef short short8 __attribute__((ext_vector_type(8)));
typedef float f32x4 __attribute__((ext_vector_type(4)));

__device__ __forceinline__ unsigned short f2bf(float f) {
  union { float f; unsigned u; } v; v.f = f;
  unsigned r = v.u + 0x7FFFu + ((v.u >> 16) & 1u);   // RNE
  return (unsigned short)(r >> 16);
}
__device__ __forceinline__ unsigned pack2(float a, float b) {
  return (unsigned)f2bf(a) | ((unsigned)f2bf(b) << 16);
}

// async global->LDS, 16B/lane; LDS dest = wave-uniform base, HW adds lane*16.
__device__ __forceinline__ void gll16(const void* g, void* l) {
  __builtin_amdgcn_global_load_lds(
      (const __attribute__((address_space(1))) void*)g,
      (__attribute__((address_space(3))) void*)l, 16, 0, 0);
}

// swizzled LDS read; tile row stride 128 B; byte ^= (row&7)<<4
__device__ __forceinline__ short8 frag_ld(const unsigned short* lds, int row, int k) {
  int addr = (row * 128 + k * 2) ^ ((row & 7) << 4);
  return *(const short8*)((const char*)lds + addr);
}

// convert one 8-float chunk fp32->bf16
__device__ __forceinline__ void cvt_chunk(const float* __restrict__ s,
    unsigned short* __restrict__ d, size_t chunk) {
  const float4* s4 = (const float4*)s + chunk * 2;
  float4 u = s4[0], v = s4[1];
  ((uint4*)d)[chunk] = make_uint4(pack2(u.x, u.y), pack2(u.z, u.w),
                                  pack2(v.x, v.y), pack2(v.z, v.w));
}

// ---------------- cvt: one chunk of each weight per thread, 6 batched loads --
__global__ __launch_bounds__(256) void k_cvt(const float* __restrict__ w1,
    const float* __restrict__ w3, const float* __restrict__ w2,
    unsigned short* __restrict__ w1b, unsigned short* __restrict__ w3b,
    unsigned short* __restrict__ w2b) {
  const size_t n8 = (size_t)(E_NUM * F_DIM * H_DIM) / 8;   // 3,670,016
  size_t i = (size_t)blockIdx.x * 256 + threadIdx.x;
  if (i >= n8) return;
  const float4* s1 = (const float4*)w1 + i * 2;
  const float4* s3 = (const float4*)w3 + i * 2;
  const float4* s2 = (const float4*)w2 + i * 2;
  float4 a1 = s1[0], b1 = s1[1];
  float4 a3 = s3[0], b3 = s3[1];
  float4 a2 = s2[0], b2 = s2[1];
  ((uint4*)w1b)[i] = make_uint4(pack2(a1.x, a1.y), pack2(a1.z, a1.w),
                                pack2(b1.x, b1.y), pack2(b1.z, b1.w));
  ((uint4*)w3b)[i] = make_uint4(pack2(a3.x, a3.y), pack2(a3.z, a3.w),
                                pack2(b3.x, b3.y), pack2(b3.z, b3.w));
  ((uint4*)w2b)[i] = make_uint4(pack2(a2.x, a2.y), pack2(a2.z, a2.w),
                                pack2(b2.x, b2.y), pack2(b2.z, b2.w));
}

// ---------------- gate + x->bf16 ---------------------------------------------
__global__ __launch_bounds__(256) void k_gate(const float* __restrict__ x,
    const float* __restrict__ gatew, int* __restrict__ counts,
    int* __restrict__ ids, float* __restrict__ gws,
    unsigned short* __restrict__ xbf) {
  int lane = threadIdx.x & 63;
  int wid  = threadIdx.x >> 6;
  int t = blockIdx.x * 4 + wid;
  const float4* x4 = (const float4*)(x + (size_t)t * H_DIM);
  const float4* g4 = (const float4*)gatew;
  float4 xv[4];
#pragma unroll
  for (int i = 0; i < 4; ++i) xv[i] = x4[lane * 4 + i];

  if (xbf) {
    uint4* xr = (uint4*)(xbf + (size_t)t * H_DIM + lane * 16);
    xr[0] = make_uint4(pack2(xv[0].x, xv[0].y), pack2(xv[0].z, xv[0].w),
                       pack2(xv[1].x, xv[1].y), pack2(xv[1].z, xv[1].w));
    xr[1] = make_uint4(pack2(xv[2].x, xv[2].y), pack2(xv[2].z, xv[2].w),
                       pack2(xv[3].x, xv[3].y), pack2(xv[3].z, xv[3].w));
  }

  double acc[E_NUM];
#pragma unroll
  for (int e = 0; e < E_NUM; ++e) acc[e] = 0.0;
#pragma unroll
  for (int i = 0; i < 4; ++i) {
#pragma unroll
    for (int e = 0; e < E_NUM; ++e) {
      float4 gv = g4[e * 256 + lane * 4 + i];
      acc[e] += (double)xv[i].x * gv.x + (double)xv[i].y * gv.y
              + (double)xv[i].z * gv.z + (double)xv[i].w * gv.w;
    }
  }
#pragma unroll
  for (int e = 0; e < E_NUM; ++e) {
#pragma unroll
    for (int off = 32; off > 0; off >>= 1)
      acc[e] += __shfl_xor(acc[e], off, 64);
  }
  if (lane == 0) {
    int i0 = 0;
#pragma unroll
    for (int e = 1; e < E_NUM; ++e) if (acc[e] > acc[i0]) i0 = e;
    int i1 = (i0 == 0) ? 1 : 0;
#pragma unroll
    for (int e = 0; e < E_NUM; ++e)
      if (e != i0 && e != i1 && acc[e] > acc[i1]) i1 = e;
    double mx = acc[i0];
    double s = 0.0;
#pragma unroll
    for (int e = 0; e < E_NUM; ++e) s += exp(acc[e] - mx);
    float p0 = (float)(exp(acc[i0] - mx) / s);
    float p1 = (float)(exp(acc[i1] - mx) / s);
    int s0 = atomicAdd(&counts[i0], 1);
    ids[i0 * T_TOK + s0] = t * 2;      gws[i0 * T_TOK + s0] = p0;
    int s1 = atomicAdd(&counts[i1], 1);
    ids[i1 * T_TOK + s1] = t * 2 + 1;  gws[i1 * T_TOK + s1] = p1;
  }
}

// ============ fast path: 16x16x32, counted-vmcnt dbuf, COMPACTED G ===========
// rule 21 staging: linear LDS dest, source chunk pre-swizzled c^(r&7),
// swizzled frag_ld on read. G row = base[e] + list position.

// ---- FFN up: BM=128 BN=64 BK=64; 512thr 8 waves, 64KB -> 2/CU = 16 waves/CU.
__global__ __launch_bounds__(512) void k_ffn1_bf(const unsigned short* __restrict__ xbf,
    const unsigned short* __restrict__ w1b, const unsigned short* __restrict__ w3b,
    const int* __restrict__ counts, const int* __restrict__ ids,
    unsigned short* __restrict__ G) {
  int e = blockIdx.z;
  int count = counts[e];
  int row0 = blockIdx.y * 128;
  if (row0 >= count) return;
  int fcol0 = blockIdx.x * 64;
  int base = 0;
#pragma unroll
  for (int j = 0; j < E_NUM; ++j) base += (j < e) ? counts[j] : 0;

  __shared__ unsigned short As[2][128 * 64];   // 32 KB
  __shared__ unsigned short B1s[2][64 * 64];   // 16 KB
  __shared__ unsigned short B3s[2][64 * 64];   // 16 KB
  __shared__ int ids_s[128];
  int t = threadIdx.x;
  if (t < 128) ids_s[t] = (row0 + t < count) ? ids[e * T_TOK + row0 + t] : 0;
  __syncthreads();

  int lane = t & 63, wid = t >> 6;             // wid in [0,8)
  const unsigned short* w1p = w1b + (size_t)e * (F_DIM * H_DIM);
  const unsigned short* w3p = w3b + (size_t)e * (F_DIM * H_DIM);

  int srck = ((lane & 7) ^ (lane >> 3)) * 8;
  unsigned offA[2];
#pragma unroll
  for (int p = 0; p < 2; ++p) {
    int r = (p * 8 + wid) * 8 + (lane >> 3);   // [0,128)
    offA[p] = (unsigned)(ids_s[r] >> 1) * H_DIM + srck;
  }
  unsigned offB = (unsigned)(fcol0 + wid * 8 + (lane >> 3)) * H_DIM + srck;

  int wr = wid >> 1, wc = wid & 1;             // 4M x 2N, wave tile 32x32
  int fr_row = lane & 15, fr_k = (lane >> 4) * 8;
  f32x4 acc1[2][2] = {};
  f32x4 acc3[2][2] = {};

  auto STAGE = [&](int b, int kk) {   // 4 gll16 per thread
#pragma unroll
    for (int p = 0; p < 2; ++p)
      gll16(xbf + offA[p] + kk, (char*)As[b] + (p * 8 + wid) * 1024);
    gll16(w1p + offB + kk, (char*)B1s[b] + wid * 1024);
    gll16(w3p + offB + kk, (char*)B3s[b] + wid * 1024);
  };

  STAGE(0, 0);

  const int NT = H_DIM / 64;  // 16
  for (int st = 0; st < NT; ++st) {
    int cur = st & 1;
    if (st + 1 < NT) {
      STAGE(cur ^ 1, (st + 1) * 64);
      asm volatile("s_waitcnt vmcnt(4)" ::: "memory");   // tile st landed (mine)
    } else {
      asm volatile("s_waitcnt vmcnt(0)" ::: "memory");
    }
    __builtin_amdgcn_s_barrier();                        // -> everyone's
#pragma unroll
    for (int ks = 0; ks < 2; ++ks) {
      short8 a[2];
#pragma unroll
      for (int m = 0; m < 2; ++m)
        a[m] = frag_ld(As[cur], wr * 32 + m * 16 + fr_row, ks * 32 + fr_k);
#pragma unroll
      for (int n = 0; n < 2; ++n) {
        short8 b1 = frag_ld(B1s[cur], wc * 32 + n * 16 + fr_row, ks * 32 + fr_k);
        short8 b3 = frag_ld(B3s[cur], wc * 32 + n * 16 + fr_row, ks * 32 + fr_k);
#pragma unroll
        for (int m = 0; m < 2; ++m) {
          acc1[m][n] = __builtin_amdgcn_mfma_f32_16x16x32_bf16(a[m], b1, acc1[m][n], 0, 0, 0);
          acc3[m][n] = __builtin_amdgcn_mfma_f32_16x16x32_bf16(a[m], b3, acc3[m][n], 0, 0, 0);
        }
      }
    }
    __builtin_amdgcn_s_barrier();
  }

  int crow = (lane >> 4) * 4, ccol = lane & 15;
#pragma unroll
  for (int m = 0; m < 2; ++m)
#pragma unroll
    for (int n = 0; n < 2; ++n)
#pragma unroll
      for (int j = 0; j < 4; ++j) {
        int rl = wr * 32 + m * 16 + crow + j;
        if (row0 + rl < count) {
          int col = fcol0 + wc * 32 + n * 16 + ccol;
          float g1 = acc1[m][n][j], g3 = acc3[m][n][j];
          float g = g1 / (1.f + __expf(-g1)) * g3;
          G[(size_t)(base + row0 + rl) * F_DIM + col] = f2bf(g);  // compacted
        }
      }
}

// ---- FFN down, split-K=2: sequential compacted-G reads; scatter S2 by slot --
// BM=128 BN=64; 256thr 4 waves; LDS 48KB -> 3/CU. (proven R19 shape)
__global__ __launch_bounds__(256) void k_ffn2_bf(const unsigned short* __restrict__ G,
    const unsigned short* __restrict__ w2b, const int* __restrict__ counts,
    const int* __restrict__ ids, const float* __restrict__ gws,
    float* __restrict__ S2) {
  int e  = blockIdx.z & 7;
  int kc = blockIdx.z >> 3;            // 0 or 1
  int count = counts[e];
  int row0 = blockIdx.y * 128;
  if (row0 >= count) return;
  int hcol0 = blockIdx.x * 64;
  int kbase = kc * KSPL;
  float* S2p = S2 + (size_t)kc * T_TOK * 2 * H_DIM;
  int base = 0;
#pragma unroll
  for (int j = 0; j < E_NUM; ++j) base += (j < e) ? counts[j] : 0;

  __shared__ unsigned short As[2][128 * 64];   // 32 KB
  __shared__ unsigned short Bs[2][64 * 64];    // 16 KB
  __shared__ int ids_s[128];
  __shared__ float gw_s[128];
  int t = threadIdx.x;
  if (t < 128) {
    int ok = (row0 + t < count);
    ids_s[t] = ok ? ids[e * T_TOK + row0 + t] : 0;
    gw_s[t]  = ok ? gws[e * T_TOK + row0 + t] : 0.f;
  }
  __syncthreads();

  int lane = t & 63, wid = t >> 6;
  const unsigned short* w2p = w2b + (size_t)e * (H_DIM * F_DIM);

  int srck = ((lane & 7) ^ (lane >> 3)) * 8;
  unsigned offA[4], offB[2];
#pragma unroll
  for (int p = 0; p < 4; ++p) {
    int r = p * 32 + wid * 8 + (lane >> 3);            // [0,128)
    int gr = base + row0 + r;
    if (gr > 2 * T_TOK - 1) gr = 2 * T_TOK - 1;        // clamp tail
    offA[p] = (unsigned)gr * F_DIM + srck;             // sequential rows
  }
#pragma unroll
  for (int p = 0; p < 2; ++p) {
    int r = p * 32 + wid * 8 + (lane >> 3);            // [0,64)
    offB[p] = (unsigned)(hcol0 + r) * F_DIM + srck;
  }

  int wm = (wid >> 1) * 64, wn = (wid & 1) * 32;
  int fr_row = lane & 15, fr_k = (lane >> 4) * 8;
  f32x4 acc[4][2] = {};

  auto STAGE = [&](int b, int kk) {   // 6 gll16 per thread
#pragma unroll
    for (int p = 0; p < 4; ++p)
      gll16(G + offA[p] + kbase + kk, (char*)As[b] + p * 4096 + wid * 1024);
#pragma unroll
    for (int p = 0; p < 2; ++p)
      gll16(w2p + offB[p] + kbase + kk, (char*)Bs[b] + p * 4096 + wid * 1024);
  };

  STAGE(0, 0);

  const int NT = KSPL / 64;  // 28
  for (int st = 0; st < NT; ++st) {
    int cur = st & 1;
    if (st + 1 < NT) {
      STAGE(cur ^ 1, (st + 1) * 64);
      asm volatile("s_waitcnt vmcnt(6)" ::: "memory");
    } else {
      asm volatile("s_waitcnt vmcnt(0)" ::: "memory");
    }
    __builtin_amdgcn_s_barrier();
#pragma unroll
    for (int ks = 0; ks < 2; ++ks) {
      short8 a[4];
#pragma unroll
      for (int m = 0; m < 4; ++m)
        a[m] = frag_ld(As[cur], wm + m * 16 + fr_row, ks * 32 + fr_k);
#pragma unroll
      for (int n = 0; n < 2; ++n) {
        short8 b = frag_ld(Bs[cur], wn + n * 16 + fr_row, ks * 32 + fr_k);
#pragma unroll
        for (int m = 0; m < 4; ++m)
          acc[m][n] = __builtin_amdgcn_mfma_f32_16x16x32_bf16(a[m], b, acc[m][n], 0, 0, 0);
      }
    }
    __builtin_amdgcn_s_barrier();
  }

  int crow = (lane >> 4) * 4, ccol = lane & 15;
#pragma unroll
  for (int m = 0; m < 4; ++m)
#pragma unroll
    for (int n = 0; n < 2; ++n)
#pragma unroll
      for (int j = 0; j < 4; ++j) {
        int rl = wm + m * 16 + crow + j;
        if (row0 + rl < count) {
          S2p[(size_t)ids_s[rl] * H_DIM + hcol0 + wn + n * 16 + ccol] =
              gw_s[rl] * acc[m][n][j];
        }
      }
}

// ---- combine: out[t] = (S2a[2t]+S2a[2t+1]) + (S2b[2t]+S2b[2t+1]) ------------
__global__ __launch_bounds__(256) void k_combine(const float* __restrict__ S2,
    float* __restrict__ out, int n4) {
  const float4* s4 = (const float4*)S2;
  const float4* s4b = (const float4*)(S2 + (size_t)T_TOK * 2 * H_DIM);
  float4* o4 = (float4*)out;
  int i = blockIdx.x * 256 + threadIdx.x;
  int stride = gridDim.x * 256;
  const int H4 = H_DIM / 4;
  for (; i < n4; i += stride) {
    int tk = i / H4, rem = i - tk * H4;
    size_t i0 = (size_t)(2 * tk) * H4 + rem;
    size_t i1 = (size_t)(2 * tk + 1) * H4 + rem;
    float4 a0 = s4[i0],  a1 = s4[i1];
    float4 b0 = s4b[i0], b1 = s4b[i1];
    o4[i] = make_float4((a0.x + a1.x) + (b0.x + b1.x),
                        (a0.y + a1.y) + (b0.y + b1.y),
                        (a0.z + a1.z) + (b0.z + b1.z),
                        (a0.w + a1.w) + (b0.w + b1.w));
  }
}

// ============ fallback path (fp32 staging, R1 kernels) =======================
__device__ __forceinline__ void stage_cvt(unsigned short* lds,
    const float* __restrict__ src, int r, int c) {
  const float4* s4 = (const float4*)src;
  float4 v[4];
#pragma unroll
  for (int i = 0; i < 4; ++i) v[i] = s4[i];
  unsigned u[8];
#pragma unroll
  for (int i = 0; i < 4; ++i) {
    u[2*i]   = pack2(v[i].x, v[i].y);
    u[2*i+1] = pack2(v[i].z, v[i].w);
  }
  int base = r * 128 + c * 2;
  int sw = (r & 7) << 4;
  *(uint4*)((char*)lds + ((base     ) ^ sw)) = make_uint4(u[0], u[1], u[2], u[3]);
  *(uint4*)((char*)lds + ((base + 16) ^ sw)) = make_uint4(u[4], u[5], u[6], u[7]);
}
__device__ __forceinline__ void stage_raw(unsigned short* lds,
    const unsigned short* __restrict__ src, int r, int c) {
  uint4 v0 = ((const uint4*)src)[0];
  uint4 v1 = ((const uint4*)src)[1];
  int base = r * 128 + c * 2;
  int sw = (r & 7) << 4;
  *(uint4*)((char*)lds + ((base     ) ^ sw)) = v0;
  *(uint4*)((char*)lds + ((base + 16) ^ sw)) = v1;
}

__global__ __launch_bounds__(256) void k_ffn1_f32(const float* __restrict__ x,
    const float* __restrict__ w1, const float* __restrict__ w3,
    const int* __restrict__ counts, const int* __restrict__ ids,
    unsigned short* __restrict__ G) {
  int e = blockIdx.z;
  int count = counts[e];
  int row0 = blockIdx.y * 128;
  if (row0 >= count) return;
  int fcol0 = blockIdx.x * 128;
  __shared__ unsigned short As[128 * 64], B1s[128 * 64], B3s[128 * 64];
  __shared__ int ids_s[128];
  int t = threadIdx.x;
  if (t < 128) ids_s[t] = (row0 + t < count) ? ids[e * T_TOK + row0 + t] : 0;
  __syncthreads();
  const float* w1p = w1 + (size_t)e * F_DIM * H_DIM;
  const float* w3p = w3 + (size_t)e * F_DIM * H_DIM;
  int lane = t & 63, wid = t >> 6;
  int wm = (wid >> 1) * 64, wn = (wid & 1) * 64;
  int fr_row = lane & 15, fr_k = (lane >> 4) * 8;
  int sr = t >> 2, sc = (t & 3) * 16;
  f32x4 acc1[4][4] = {};
  f32x4 acc3[4][4] = {};
  for (int kk = 0; kk < H_DIM; kk += 64) {
#pragma unroll
    for (int p = 0; p < 2; ++p) {
      int r = p * 64 + sr;
      int id = ids_s[r];
      stage_cvt(As,  x   + (size_t)(id >> 1) * H_DIM   + kk + sc, r, sc);
      stage_cvt(B1s, w1p + (size_t)(fcol0 + r) * H_DIM + kk + sc, r, sc);
      stage_cvt(B3s, w3p + (size_t)(fcol0 + r) * H_DIM + kk + sc, r, sc);
    }
    __syncthreads();
#pragma unroll
    for (int ks = 0; ks < 2; ++ks) {
      short8 a[4];
#pragma unroll
      for (int m = 0; m < 4; ++m)
        a[m] = frag_ld(As, wm + m * 16 + fr_row, ks * 32 + fr_k);
#pragma unroll
      for (int n = 0; n < 4; ++n) {
        short8 b1 = frag_ld(B1s, wn + n * 16 + fr_row, ks * 32 + fr_k);
        short8 b3 = frag_ld(B3s, wn + n * 16 + fr_row, ks * 32 + fr_k);
#pragma unroll
        for (int m = 0; m < 4; ++m) {
          acc1[m][n] = __builtin_amdgcn_mfma_f32_16x16x32_bf16(a[m], b1, acc1[m][n], 0, 0, 0);
          acc3[m][n] = __builtin_amdgcn_mfma_f32_16x16x32_bf16(a[m], b3, acc3[m][n], 0, 0, 0);
        }
      }
    }
    __syncthreads();
  }
  int crow = (lane >> 4) * 4, ccol = lane & 15;
#pragma unroll
  for (int m = 0; m < 4; ++m)
#pragma unroll
    for (int n = 0; n < 4; ++n)
#pragma unroll
      for (int j = 0; j < 4; ++j) {
        int rl = wm + m * 16 + crow + j;
        if (row0 + rl < count) {
          int id = ids_s[rl];
          int col = fcol0 + wn + n * 16 + ccol;
          float g1 = acc1[m][n][j], g3 = acc3[m][n][j];
          float g = g1 / (1.f + __expf(-g1)) * g3;
          G[(size_t)id * F_DIM + col] = f2bf(g);
        }
      }
}

__global__ __launch_bounds__(256) void k_ffn2_f32(const unsigned short* __restrict__ G,
    const float* __restrict__ w2, const int* __restrict__ counts,
    const int* __restrict__ ids, const float* __restrict__ gws,
    float* __restrict__ out) {
  int e = blockIdx.z;
  int count = counts[e];
  int row0 = blockIdx.y * 128;
  if (row0 >= count) return;
  int hcol0 = blockIdx.x * 128;
  __shared__ unsigned short As[128 * 64], Bs[128 * 64];
  __shared__ int ids_s[128];
  __shared__ float gw_s[128];
  int t = threadIdx.x;
  if (t < 128) {
    int ok = (row0 + t < count);
    ids_s[t] = ok ? ids[e * T_TOK + row0 + t] : 0;
    gw_s[t]  = ok ? gws[e * T_TOK + row0 + t] : 0.f;
  }
  __syncthreads();
  const float* w2p = w2 + (size_t)e * H_DIM * F_DIM;
  int lane = t & 63, wid = t >> 6;
  int wm = (wid >> 1) * 64, wn = (wid & 1) * 64;
  int fr_row = lane & 15, fr_k = (lane >> 4) * 8;
  int sr = t >> 2, sc = (t & 3) * 16;
  f32x4 acc[4][4] = {};
  for (int kk = 0; kk < F_DIM; kk += 64) {
#pragma unroll
    for (int p = 0; p < 2; ++p) {
      int r = p * 64 + sr;
      stage_raw(As, G + (size_t)ids_s[r] * F_DIM + kk + sc, r, sc);
      stage_cvt(Bs, w2p + (size_t)(hcol0 + r) * F_DIM + kk + sc, r, sc);
    }
    __syncthreads();
#pragma unroll
    for (int ks = 0; ks < 2; ++ks) {
      short8 a[4];
#pragma unroll
      for (int m = 0; m < 4; ++m)
        a[m] = frag_ld(As, wm + m * 16 + fr_row, ks * 32 + fr_k);
#pragma unroll
      for (int n = 0; n < 4; ++n) {
        short8 b = frag_ld(Bs, wn + n * 16 + fr_row, ks * 32 + fr_k);
#pragma unroll
        for (int m = 0; m < 4; ++m)
          acc[m][n] = __builtin_amdgcn_mfma_f32_16x16x32_bf16(a[m], b, acc[m][n], 0, 0, 0);
      }
    }
    __syncthreads();
  }
  int crow = (lane >> 4) * 4, ccol = lane & 15;
#pragma unroll
  for (int m = 0; m < 4; ++m)
#pragma unroll
    for (int n = 0; n < 4; ++n)
#pragma unroll
      for (int j = 0; j < 4; ++j) {
        int rl = wm + m * 16 + crow + j;
        if (row0 + rl < count) {
          int tok = ids_s[rl] >> 1;
          atomicAdd(&out[(size_t)tok * H_DIM + hcol0 + wn + n * 16 + ccol],
                    gw_s[rl] * acc[m][n][j]);
        }
      }
}

// ---------------- launch -----------------------------------------------------
extern "C" void kernel_launch(void* const* d_in, const int* in_sizes, int n_in,
                              void* d_out, int out_size, void* d_ws, size_t ws_size,
                              hipStream_t stream) {
  const float* x     = (const float*)d_in[0];
  const float* gatew = (const float*)d_in[1];
  const float* w1    = (const float*)d_in[2];
  const float* w3    = (const float*)d_in[3];
  const float* w2    = (const float*)d_in[4];
  float* out = (float*)d_out;

  char* ws = (char*)d_ws;
  int*   counts = (int*)ws;
  int*   ids    = (int*)(ws + 4096);
  float* gws    = (float*)(ws + 4096 + E_NUM * T_TOK * 4);

  const size_t WBYTES = (size_t)E_NUM * F_DIM * H_DIM * 2;  // 58,720,256
  unsigned short* xbf = (unsigned short*)(ws + (1ull << 20));
  unsigned short* w1b = (unsigned short*)(ws + (16ull << 20));
  unsigned short* w3b = (unsigned short*)(ws + (16ull << 20) + WBYTES);
  unsigned short* w2b = (unsigned short*)(ws + (16ull << 20) + 2 * WBYTES);
  unsigned short* Gf  = (unsigned short*)(ws + (16ull << 20) + 3 * WBYTES);
  // S2: 2 split-K partials = 67.1 MB; aliases w1b+w3b (dead after ffn1);
  // w2b (at +117.4MB) and Gf (at +176MB) stay clear.
  float* S2 = (float*)w1b;
  size_t required = (16ull << 20) + 4 * WBYTES;              // ~252 MB

  hipMemsetAsync(counts, 0, E_NUM * sizeof(int), stream);

  if (ws_size >= required) {
    const int n8 = (E_NUM * F_DIM * H_DIM) / 8;   // 3,670,016
    k_cvt<<<dim3((n8 + 255) / 256), dim3(256), 0, stream>>>(
        w1, w3, w2, w1b, w3b, w2b);
    k_gate<<<dim3(T_TOK / 4), dim3(256), 0, stream>>>(
        x, gatew, counts, ids, gws, xbf);
    k_ffn1_bf<<<dim3(F_DIM / 64, T_TOK / 128, E_NUM), dim3(512), 0, stream>>>(
        xbf, w1b, w3b, counts, ids, Gf);
    k_ffn2_bf<<<dim3(H_DIM / 64, T_TOK / 128, E_NUM * 2), dim3(256), 0, stream>>>(
        Gf, w2b, counts, ids, gws, S2);
    k_combine<<<dim3(1024), dim3(256), 0, stream>>>(
        S2, out, T_TOK * H_DIM / 4);
  } else {
    hipMemsetAsync(d_out, 0, (size_t)out_size * sizeof(float), stream);
    unsigned short* G = (unsigned short*)(ws + (1ull << 20));
    k_gate<<<dim3(T_TOK / 4), dim3(256), 0, stream>>>(
        x, gatew, counts, ids, gws, (unsigned short*)nullptr);
    k_ffn1_f32<<<dim3(F_DIM / 128, T_TOK / 128, E_NUM), dim3(256), 0, stream>>>(
        x, w1, w3, counts, ids, G);
    k_ffn2_f32<<<dim3(H_DIM / 128, T_TOK / 128, E_NUM), dim3(256), 0, stream>>>(
        G, w2, counts, ids, gws, out);
  }
}

// Round 23
// 460.586 us; speedup vs baseline: 1.0130x; 1.0130x over previous
//
#include <hip/hip_runtime.h>
#include <hip/hip_bf16.h>
#include <math.h>

// MixtralMoE: B=1, S=4096, H=1024, E=8, F=3584, K=2
// inputs: hidden_states, gate_w, w1, w3, w2 (all fp32); output fp32 [4096,1024]

#define T_TOK 4096
#define H_DIM 1024
#define E_NUM 8
#define F_DIM 3584
#define KSPL 1792           // ffn2 split-K chunk (2 chunks of 28 K-steps)

typedef short short8 __attribute__((ext_vector_type(8)));
typedef float f32x4 __attribute__((ext_vector_type(4)));
typedef float f32x4e __attribute__((ext_vector_type(4)));
typedef unsigned u32x4e __attribute__((ext_vector_type(4)));

__device__ __forceinline__ unsigned short f2bf(float f) {
  union { float f; unsigned u; } v; v.f = f;
  unsigned r = v.u + 0x7FFFu + ((v.u >> 16) & 1u);   // RNE
  return (unsigned short)(r >> 16);
}
__device__ __forceinline__ unsigned pack2(float a, float b) {
  return (unsigned)f2bf(a) | ((unsigned)f2bf(b) << 16);
}

// async global->LDS, 16B/lane; LDS dest = wave-uniform base, HW adds lane*16.
__device__ __forceinline__ void gll16(const void* g, void* l) {
  __builtin_amdgcn_global_load_lds(
      (const __attribute__((address_space(1))) void*)g,
      (__attribute__((address_space(3))) void*)l, 16, 0, 0);
}

// swizzled LDS read; tile row stride 128 B; byte ^= (row&7)<<4
__device__ __forceinline__ short8 frag_ld(const unsigned short* lds, int row, int k) {
  int addr = (row * 128 + k * 2) ^ ((row & 7) << 4);
  return *(const short8*)((const char*)lds + addr);
}

// ---------------- cvtgate: gate (blocks 0..1023) + one-shot NT cvt (rest) ----
// cvt role: per thread one chunk of each weight, 6 nontemporal loads batched,
// 3 nontemporal stores (read-once/write-once streams; keep L2 for reads).
__global__ __launch_bounds__(256) void k_cvtgate(const float* __restrict__ x,
    const float* __restrict__ gatew, int* __restrict__ counts,
    int* __restrict__ ids, float* __restrict__ gws,
    unsigned short* __restrict__ xbf,
    const float* __restrict__ w1, const float* __restrict__ w3,
    const float* __restrict__ w2,
    unsigned short* __restrict__ w1b, unsigned short* __restrict__ w3b,
    unsigned short* __restrict__ w2b) {
  if ((int)blockIdx.x >= 1024) {
    const size_t n8 = (size_t)(E_NUM * F_DIM * H_DIM) / 8;   // 3,670,016
    size_t i = (size_t)((int)blockIdx.x - 1024) * 256 + threadIdx.x;
    if (i >= n8) return;
    const f32x4e* s1 = (const f32x4e*)w1 + i * 2;
    const f32x4e* s3 = (const f32x4e*)w3 + i * 2;
    const f32x4e* s2 = (const f32x4e*)w2 + i * 2;
    f32x4e a1 = __builtin_nontemporal_load(s1);
    f32x4e b1 = __builtin_nontemporal_load(s1 + 1);
    f32x4e a3 = __builtin_nontemporal_load(s3);
    f32x4e b3 = __builtin_nontemporal_load(s3 + 1);
    f32x4e a2 = __builtin_nontemporal_load(s2);
    f32x4e b2 = __builtin_nontemporal_load(s2 + 1);
    u32x4e r1 = { pack2(a1.x, a1.y), pack2(a1.z, a1.w),
                  pack2(b1.x, b1.y), pack2(b1.z, b1.w) };
    u32x4e r3 = { pack2(a3.x, a3.y), pack2(a3.z, a3.w),
                  pack2(b3.x, b3.y), pack2(b3.z, b3.w) };
    u32x4e r2 = { pack2(a2.x, a2.y), pack2(a2.z, a2.w),
                  pack2(b2.x, b2.y), pack2(b2.z, b2.w) };
    __builtin_nontemporal_store(r1, (u32x4e*)w1b + i);
    __builtin_nontemporal_store(r3, (u32x4e*)w3b + i);
    __builtin_nontemporal_store(r2, (u32x4e*)w2b + i);
    return;
  }
  // gate role (identical math to proven k_gate)
  int lane = threadIdx.x & 63;
  int wid  = threadIdx.x >> 6;
  int t = blockIdx.x * 4 + wid;
  const float4* x4 = (const float4*)(x + (size_t)t * H_DIM);
  const float4* g4 = (const float4*)gatew;
  float4 xv[4];
#pragma unroll
  for (int i = 0; i < 4; ++i) xv[i] = x4[lane * 4 + i];

  uint4* xr = (uint4*)(xbf + (size_t)t * H_DIM + lane * 16);
  xr[0] = make_uint4(pack2(xv[0].x, xv[0].y), pack2(xv[0].z, xv[0].w),
                     pack2(xv[1].x, xv[1].y), pack2(xv[1].z, xv[1].w));
  xr[1] = make_uint4(pack2(xv[2].x, xv[2].y), pack2(xv[2].z, xv[2].w),
                     pack2(xv[3].x, xv[3].y), pack2(xv[3].z, xv[3].w));

  double acc[E_NUM];
#pragma unroll
  for (int e = 0; e < E_NUM; ++e) acc[e] = 0.0;
#pragma unroll
  for (int i = 0; i < 4; ++i) {
#pragma unroll
    for (int e = 0; e < E_NUM; ++e) {
      float4 gv = g4[e * 256 + lane * 4 + i];
      acc[e] += (double)xv[i].x * gv.x + (double)xv[i].y * gv.y
              + (double)xv[i].z * gv.z + (double)xv[i].w * gv.w;
    }
  }
#pragma unroll
  for (int e = 0; e < E_NUM; ++e) {
#pragma unroll
    for (int off = 32; off > 0; off >>= 1)
      acc[e] += __shfl_xor(acc[e], off, 64);
  }
  if (lane == 0) {
    int i0 = 0;
#pragma unroll
    for (int e = 1; e < E_NUM; ++e) if (acc[e] > acc[i0]) i0 = e;
    int i1 = (i0 == 0) ? 1 : 0;
#pragma unroll
    for (int e = 0; e < E_NUM; ++e)
      if (e != i0 && e != i1 && acc[e] > acc[i1]) i1 = e;
    double mx = acc[i0];
    double s = 0.0;
#pragma unroll
    for (int e = 0; e < E_NUM; ++e) s += exp(acc[e] - mx);
    float p0 = (float)(exp(acc[i0] - mx) / s);
    float p1 = (float)(exp(acc[i1] - mx) / s);
    int s0 = atomicAdd(&counts[i0], 1);
    ids[i0 * T_TOK + s0] = t * 2;      gws[i0 * T_TOK + s0] = p0;
    int s1 = atomicAdd(&counts[i1], 1);
    ids[i1 * T_TOK + s1] = t * 2 + 1;  gws[i1 * T_TOK + s1] = p1;
  }
}

// ---------------- gate (fallback path) ---------------------------------------
__global__ __launch_bounds__(256) void k_gate(const float* __restrict__ x,
    const float* __restrict__ gatew, int* __restrict__ counts,
    int* __restrict__ ids, float* __restrict__ gws,
    unsigned short* __restrict__ xbf) {
  int lane = threadIdx.x & 63;
  int wid  = threadIdx.x >> 6;
  int t = blockIdx.x * 4 + wid;
  const float4* x4 = (const float4*)(x + (size_t)t * H_DIM);
  const float4* g4 = (const float4*)gatew;
  float4 xv[4];
#pragma unroll
  for (int i = 0; i < 4; ++i) xv[i] = x4[lane * 4 + i];

  if (xbf) {
    uint4* xr = (uint4*)(xbf + (size_t)t * H_DIM + lane * 16);
    xr[0] = make_uint4(pack2(xv[0].x, xv[0].y), pack2(xv[0].z, xv[0].w),
                       pack2(xv[1].x, xv[1].y), pack2(xv[1].z, xv[1].w));
    xr[1] = make_uint4(pack2(xv[2].x, xv[2].y), pack2(xv[2].z, xv[2].w),
                       pack2(xv[3].x, xv[3].y), pack2(xv[3].z, xv[3].w));
  }

  double acc[E_NUM];
#pragma unroll
  for (int e = 0; e < E_NUM; ++e) acc[e] = 0.0;
#pragma unroll
  for (int i = 0; i < 4; ++i) {
#pragma unroll
    for (int e = 0; e < E_NUM; ++e) {
      float4 gv = g4[e * 256 + lane * 4 + i];
      acc[e] += (double)xv[i].x * gv.x + (double)xv[i].y * gv.y
              + (double)xv[i].z * gv.z + (double)xv[i].w * gv.w;
    }
  }
#pragma unroll
  for (int e = 0; e < E_NUM; ++e) {
#pragma unroll
    for (int off = 32; off > 0; off >>= 1)
      acc[e] += __shfl_xor(acc[e], off, 64);
  }
  if (lane == 0) {
    int i0 = 0;
#pragma unroll
    for (int e = 1; e < E_NUM; ++e) if (acc[e] > acc[i0]) i0 = e;
    int i1 = (i0 == 0) ? 1 : 0;
#pragma unroll
    for (int e = 0; e < E_NUM; ++e)
      if (e != i0 && e != i1 && acc[e] > acc[i1]) i1 = e;
    double mx = acc[i0];
    double s = 0.0;
#pragma unroll
    for (int e = 0; e < E_NUM; ++e) s += exp(acc[e] - mx);
    float p0 = (float)(exp(acc[i0] - mx) / s);
    float p1 = (float)(exp(acc[i1] - mx) / s);
    int s0 = atomicAdd(&counts[i0], 1);
    ids[i0 * T_TOK + s0] = t * 2;      gws[i0 * T_TOK + s0] = p0;
    int s1 = atomicAdd(&counts[i1], 1);
    ids[i1 * T_TOK + s1] = t * 2 + 1;  gws[i1 * T_TOK + s1] = p1;
  }
}

// ============ fast path: 16x16x32, counted-vmcnt dbuf, COMPACTED G ===========
// rule 21 staging: linear LDS dest, source chunk pre-swizzled c^(r&7),
// swizzled frag_ld on read. G row = base[e] + list position.

// ---- FFN up: BM=128 BN=64 BK=64; 512thr 8 waves, 64KB -> 2/CU = 16 waves/CU.
__global__ __launch_bounds__(512) void k_ffn1_bf(const unsigned short* __restrict__ xbf,
    const unsigned short* __restrict__ w1b, const unsigned short* __restrict__ w3b,
    const int* __restrict__ counts, const int* __restrict__ ids,
    unsigned short* __restrict__ G) {
  int e = blockIdx.z;
  int count = counts[e];
  int row0 = blockIdx.y * 128;
  if (row0 >= count) return;
  int fcol0 = blockIdx.x * 64;
  int base = 0;
#pragma unroll
  for (int j = 0; j < E_NUM; ++j) base += (j < e) ? counts[j] : 0;

  __shared__ unsigned short As[2][128 * 64];   // 32 KB
  __shared__ unsigned short B1s[2][64 * 64];   // 16 KB
  __shared__ unsigned short B3s[2][64 * 64];   // 16 KB
  __shared__ int ids_s[128];
  int t = threadIdx.x;
  if (t < 128) ids_s[t] = (row0 + t < count) ? ids[e * T_TOK + row0 + t] : 0;
  __syncthreads();

  int lane = t & 63, wid = t >> 6;             // wid in [0,8)
  const unsigned short* w1p = w1b + (size_t)e * (F_DIM * H_DIM);
  const unsigned short* w3p = w3b + (size_t)e * (F_DIM * H_DIM);

  int srck = ((lane & 7) ^ (lane >> 3)) * 8;
  unsigned offA[2];
#pragma unroll
  for (int p = 0; p < 2; ++p) {
    int r = (p * 8 + wid) * 8 + (lane >> 3);   // [0,128)
    offA[p] = (unsigned)(ids_s[r] >> 1) * H_DIM + srck;
  }
  unsigned offB = (unsigned)(fcol0 + wid * 8 + (lane >> 3)) * H_DIM + srck;

  int wr = wid >> 1, wc = wid & 1;             // 4M x 2N, wave tile 32x32
  int fr_row = lane & 15, fr_k = (lane >> 4) * 8;
  f32x4 acc1[2][2] = {};
  f32x4 acc3[2][2] = {};

  auto STAGE = [&](int b, int kk) {   // 4 gll16 per thread
#pragma unroll
    for (int p = 0; p < 2; ++p)
      gll16(xbf + offA[p] + kk, (char*)As[b] + (p * 8 + wid) * 1024);
    gll16(w1p + offB + kk, (char*)B1s[b] + wid * 1024);
    gll16(w3p + offB + kk, (char*)B3s[b] + wid * 1024);
  };

  STAGE(0, 0);

  const int NT = H_DIM / 64;  // 16
  for (int st = 0; st < NT; ++st) {
    int cur = st & 1;
    if (st + 1 < NT) {
      STAGE(cur ^ 1, (st + 1) * 64);
      asm volatile("s_waitcnt vmcnt(4)" ::: "memory");   // tile st landed (mine)
    } else {
      asm volatile("s_waitcnt vmcnt(0)" ::: "memory");
    }
    __builtin_amdgcn_s_barrier();                        // -> everyone's
#pragma unroll
    for (int ks = 0; ks < 2; ++ks) {
      short8 a[2];
#pragma unroll
      for (int m = 0; m < 2; ++m)
        a[m] = frag_ld(As[cur], wr * 32 + m * 16 + fr_row, ks * 32 + fr_k);
#pragma unroll
      for (int n = 0; n < 2; ++n) {
        short8 b1 = frag_ld(B1s[cur], wc * 32 + n * 16 + fr_row, ks * 32 + fr_k);
        short8 b3 = frag_ld(B3s[cur], wc * 32 + n * 16 + fr_row, ks * 32 + fr_k);
#pragma unroll
        for (int m = 0; m < 2; ++m) {
          acc1[m][n] = __builtin_amdgcn_mfma_f32_16x16x32_bf16(a[m], b1, acc1[m][n], 0, 0, 0);
          acc3[m][n] = __builtin_amdgcn_mfma_f32_16x16x32_bf16(a[m], b3, acc3[m][n], 0, 0, 0);
        }
      }
    }
    __builtin_amdgcn_s_barrier();
  }

  int crow = (lane >> 4) * 4, ccol = lane & 15;
#pragma unroll
  for (int m = 0; m < 2; ++m)
#pragma unroll
    for (int n = 0; n < 2; ++n)
#pragma unroll
      for (int j = 0; j < 4; ++j) {
        int rl = wr * 32 + m * 16 + crow + j;
        if (row0 + rl < count) {
          int col = fcol0 + wc * 32 + n * 16 + ccol;
          float g1 = acc1[m][n][j], g3 = acc3[m][n][j];
          float g = g1 / (1.f + __expf(-g1)) * g3;
          G[(size_t)(base + row0 + rl) * F_DIM + col] = f2bf(g);  // compacted
        }
      }
}

// ---- FFN down, split-K=2: sequential compacted-G reads; scatter S2 by slot --
// BM=128 BN=64; 256thr 4 waves; LDS 48KB -> 3/CU. (proven R19 shape)
__global__ __launch_bounds__(256) void k_ffn2_bf(const unsigned short* __restrict__ G,
    const unsigned short* __restrict__ w2b, const int* __restrict__ counts,
    const int* __restrict__ ids, const float* __restrict__ gws,
    float* __restrict__ S2) {
  int e  = blockIdx.z & 7;
  int kc = blockIdx.z >> 3;            // 0 or 1
  int count = counts[e];
  int row0 = blockIdx.y * 128;
  if (row0 >= count) return;
  int hcol0 = blockIdx.x * 64;
  int kbase = kc * KSPL;
  float* S2p = S2 + (size_t)kc * T_TOK * 2 * H_DIM;
  int base = 0;
#pragma unroll
  for (int j = 0; j < E_NUM; ++j) base += (j < e) ? counts[j] : 0;

  __shared__ unsigned short As[2][128 * 64];   // 32 KB
  __shared__ unsigned short Bs[2][64 * 64];    // 16 KB
  __shared__ int ids_s[128];
  __shared__ float gw_s[128];
  int t = threadIdx.x;
  if (t < 128) {
    int ok = (row0 + t < count);
    ids_s[t] = ok ? ids[e * T_TOK + row0 + t] : 0;
    gw_s[t]  = ok ? gws[e * T_TOK + row0 + t] : 0.f;
  }
  __syncthreads();

  int lane = t & 63, wid = t >> 6;
  const unsigned short* w2p = w2b + (size_t)e * (H_DIM * F_DIM);

  int srck = ((lane & 7) ^ (lane >> 3)) * 8;
  unsigned offA[4], offB[2];
#pragma unroll
  for (int p = 0; p < 4; ++p) {
    int r = p * 32 + wid * 8 + (lane >> 3);            // [0,128)
    int gr = base + row0 + r;
    if (gr > 2 * T_TOK - 1) gr = 2 * T_TOK - 1;        // clamp tail
    offA[p] = (unsigned)gr * F_DIM + srck;             // sequential rows
  }
#pragma unroll
  for (int p = 0; p < 2; ++p) {
    int r = p * 32 + wid * 8 + (lane >> 3);            // [0,64)
    offB[p] = (unsigned)(hcol0 + r) * F_DIM + srck;
  }

  int wm = (wid >> 1) * 64, wn = (wid & 1) * 32;
  int fr_row = lane & 15, fr_k = (lane >> 4) * 8;
  f32x4 acc[4][2] = {};

  auto STAGE = [&](int b, int kk) {   // 6 gll16 per thread
#pragma unroll
    for (int p = 0; p < 4; ++p)
      gll16(G + offA[p] + kbase + kk, (char*)As[b] + p * 4096 + wid * 1024);
#pragma unroll
    for (int p = 0; p < 2; ++p)
      gll16(w2p + offB[p] + kbase + kk, (char*)Bs[b] + p * 4096 + wid * 1024);
  };

  STAGE(0, 0);

  const int NT = KSPL / 64;  // 28
  for (int st = 0; st < NT; ++st) {
    int cur = st & 1;
    if (st + 1 < NT) {
      STAGE(cur ^ 1, (st + 1) * 64);
      asm volatile("s_waitcnt vmcnt(6)" ::: "memory");
    } else {
      asm volatile("s_waitcnt vmcnt(0)" ::: "memory");
    }
    __builtin_amdgcn_s_barrier();
#pragma unroll
    for (int ks = 0; ks < 2; ++ks) {
      short8 a[4];
#pragma unroll
      for (int m = 0; m < 4; ++m)
        a[m] = frag_ld(As[cur], wm + m * 16 + fr_row, ks * 32 + fr_k);
#pragma unroll
      for (int n = 0; n < 2; ++n) {
        short8 b = frag_ld(Bs[cur], wn + n * 16 + fr_row, ks * 32 + fr_k);
#pragma unroll
        for (int m = 0; m < 4; ++m)
          acc[m][n] = __builtin_amdgcn_mfma_f32_16x16x32_bf16(a[m], b, acc[m][n], 0, 0, 0);
      }
    }
    __builtin_amdgcn_s_barrier();
  }

  int crow = (lane >> 4) * 4, ccol = lane & 15;
#pragma unroll
  for (int m = 0; m < 4; ++m)
#pragma unroll
    for (int n = 0; n < 2; ++n)
#pragma unroll
      for (int j = 0; j < 4; ++j) {
        int rl = wm + m * 16 + crow + j;
        if (row0 + rl < count) {
          S2p[(size_t)ids_s[rl] * H_DIM + hcol0 + wn + n * 16 + ccol] =
              gw_s[rl] * acc[m][n][j];
        }
      }
}

// ---- combine: out[t] = (S2a[2t]+S2a[2t+1]) + (S2b[2t]+S2b[2t+1]) ------------
__global__ __launch_bounds__(256) void k_combine(const float* __restrict__ S2,
    float* __restrict__ out, int n4) {
  const float4* s4 = (const float4*)S2;
  const float4* s4b = (const float4*)(S2 + (size_t)T_TOK * 2 * H_DIM);
  float4* o4 = (float4*)out;
  int i = blockIdx.x * 256 + threadIdx.x;
  int stride = gridDim.x * 256;
  const int H4 = H_DIM / 4;
  for (; i < n4; i += stride) {
    int tk = i / H4, rem = i - tk * H4;
    size_t i0 = (size_t)(2 * tk) * H4 + rem;
    size_t i1 = (size_t)(2 * tk + 1) * H4 + rem;
    float4 a0 = s4[i0],  a1 = s4[i1];
    float4 b0 = s4b[i0], b1 = s4b[i1];
    o4[i] = make_float4((a0.x + a1.x) + (b0.x + b1.x),
                        (a0.y + a1.y) + (b0.y + b1.y),
                        (a0.z + a1.z) + (b0.z + b1.z),
                        (a0.w + a1.w) + (b0.w + b1.w));
  }
}

// ============ fallback path (fp32 staging, R1 kernels) =======================
__device__ __forceinline__ void stage_cvt(unsigned short* lds,
    const float* __restrict__ src, int r, int c) {
  const float4* s4 = (const float4*)src;
  float4 v[4];
#pragma unroll
  for (int i = 0; i < 4; ++i) v[i] = s4[i];
  unsigned u[8];
#pragma unroll
  for (int i = 0; i < 4; ++i) {
    u[2*i]   = pack2(v[i].x, v[i].y);
    u[2*i+1] = pack2(v[i].z, v[i].w);
  }
  int base = r * 128 + c * 2;
  int sw = (r & 7) << 4;
  *(uint4*)((char*)lds + ((base     ) ^ sw)) = make_uint4(u[0], u[1], u[2], u[3]);
  *(uint4*)((char*)lds + ((base + 16) ^ sw)) = make_uint4(u[4], u[5], u[6], u[7]);
}
__device__ __forceinline__ void stage_raw(unsigned short* lds,
    const unsigned short* __restrict__ src, int r, int c) {
  uint4 v0 = ((const uint4*)src)[0];
  uint4 v1 = ((const uint4*)src)[1];
  int base = r * 128 + c * 2;
  int sw = (r & 7) << 4;
  *(uint4*)((char*)lds + ((base     ) ^ sw)) = v0;
  *(uint4*)((char*)lds + ((base + 16) ^ sw)) = v1;
}

__global__ __launch_bounds__(256) void k_ffn1_f32(const float* __restrict__ x,
    const float* __restrict__ w1, const float* __restrict__ w3,
    const int* __restrict__ counts, const int* __restrict__ ids,
    unsigned short* __restrict__ G) {
  int e = blockIdx.z;
  int count = counts[e];
  int row0 = blockIdx.y * 128;
  if (row0 >= count) return;
  int fcol0 = blockIdx.x * 128;
  __shared__ unsigned short As[128 * 64], B1s[128 * 64], B3s[128 * 64];
  __shared__ int ids_s[128];
  int t = threadIdx.x;
  if (t < 128) ids_s[t] = (row0 + t < count) ? ids[e * T_TOK + row0 + t] : 0;
  __syncthreads();
  const float* w1p = w1 + (size_t)e * F_DIM * H_DIM;
  const float* w3p = w3 + (size_t)e * F_DIM * H_DIM;
  int lane = t & 63, wid = t >> 6;
  int wm = (wid >> 1) * 64, wn = (wid & 1) * 64;
  int fr_row = lane & 15, fr_k = (lane >> 4) * 8;
  int sr = t >> 2, sc = (t & 3) * 16;
  f32x4 acc1[4][4] = {};
  f32x4 acc3[4][4] = {};
  for (int kk = 0; kk < H_DIM; kk += 64) {
#pragma unroll
    for (int p = 0; p < 2; ++p) {
      int r = p * 64 + sr;
      int id = ids_s[r];
      stage_cvt(As,  x   + (size_t)(id >> 1) * H_DIM   + kk + sc, r, sc);
      stage_cvt(B1s, w1p + (size_t)(fcol0 + r) * H_DIM + kk + sc, r, sc);
      stage_cvt(B3s, w3p + (size_t)(fcol0 + r) * H_DIM + kk + sc, r, sc);
    }
    __syncthreads();
#pragma unroll
    for (int ks = 0; ks < 2; ++ks) {
      short8 a[4];
#pragma unroll
      for (int m = 0; m < 4; ++m)
        a[m] = frag_ld(As, wm + m * 16 + fr_row, ks * 32 + fr_k);
#pragma unroll
      for (int n = 0; n < 4; ++n) {
        short8 b1 = frag_ld(B1s, wn + n * 16 + fr_row, ks * 32 + fr_k);
        short8 b3 = frag_ld(B3s, wn + n * 16 + fr_row, ks * 32 + fr_k);
#pragma unroll
        for (int m = 0; m < 4; ++m) {
          acc1[m][n] = __builtin_amdgcn_mfma_f32_16x16x32_bf16(a[m], b1, acc1[m][n], 0, 0, 0);
          acc3[m][n] = __builtin_amdgcn_mfma_f32_16x16x32_bf16(a[m], b3, acc3[m][n], 0, 0, 0);
        }
      }
    }
    __syncthreads();
  }
  int crow = (lane >> 4) * 4, ccol = lane & 15;
#pragma unroll
  for (int m = 0; m < 4; ++m)
#pragma unroll
    for (int n = 0; n < 4; ++n)
#pragma unroll
      for (int j = 0; j < 4; ++j) {
        int rl = wm + m * 16 + crow + j;
        if (row0 + rl < count) {
          int id = ids_s[rl];
          int col = fcol0 + wn + n * 16 + ccol;
          float g1 = acc1[m][n][j], g3 = acc3[m][n][j];
          float g = g1 / (1.f + __expf(-g1)) * g3;
          G[(size_t)id * F_DIM + col] = f2bf(g);
        }
      }
}

__global__ __launch_bounds__(256) void k_ffn2_f32(const unsigned short* __restrict__ G,
    const float* __restrict__ w2, const int* __restrict__ counts,
    const int* __restrict__ ids, const float* __restrict__ gws,
    float* __restrict__ out) {
  int e = blockIdx.z;
  int count = counts[e];
  int row0 = blockIdx.y * 128;
  if (row0 >= count) return;
  int hcol0 = blockIdx.x * 128;
  __shared__ unsigned short As[128 * 64], Bs[128 * 64];
  __shared__ int ids_s[128];
  __shared__ float gw_s[128];
  int t = threadIdx.x;
  if (t < 128) {
    int ok = (row0 + t < count);
    ids_s[t] = ok ? ids[e * T_TOK + row0 + t] : 0;
    gw_s[t]  = ok ? gws[e * T_TOK + row0 + t] : 0.f;
  }
  __syncthreads();
  const float* w2p = w2 + (size_t)e * H_DIM * F_DIM;
  int lane = t & 63, wid = t >> 6;
  int wm = (wid >> 1) * 64, wn = (wid & 1) * 64;
  int fr_row = lane & 15, fr_k = (lane >> 4) * 8;
  int sr = t >> 2, sc = (t & 3) * 16;
  f32x4 acc[4][4] = {};
  for (int kk = 0; kk < F_DIM; kk += 64) {
#pragma unroll
    for (int p = 0; p < 2; ++p) {
      int r = p * 64 + sr;
      stage_raw(As, G + (size_t)ids_s[r] * F_DIM + kk + sc, r, sc);
      stage_cvt(Bs, w2p + (size_t)(hcol0 + r) * F_DIM + kk + sc, r, sc);
    }
    __syncthreads();
#pragma unroll
    for (int ks = 0; ks < 2; ++ks) {
      short8 a[4];
#pragma unroll
      for (int m = 0; m < 4; ++m)
        a[m] = frag_ld(As, wm + m * 16 + fr_row, ks * 32 + fr_k);
#pragma unroll
      for (int n = 0; n < 4; ++n) {
        short8 b = frag_ld(Bs, wn + n * 16 + fr_row, ks * 32 + fr_k);
#pragma unroll
        for (int m = 0; m < 4; ++m)
          acc[m][n] = __builtin_amdgcn_mfma_f32_16x16x32_bf16(a[m], b, acc[m][n], 0, 0, 0);
      }
    }
    __syncthreads();
  }
  int crow = (lane >> 4) * 4, ccol = lane & 15;
#pragma unroll
  for (int m = 0; m < 4; ++m)
#pragma unroll
    for (int n = 0; n < 4; ++n)
#pragma unroll
      for (int j = 0; j < 4; ++j) {
        int rl = wm + m * 16 + crow + j;
        if (row0 + rl < count) {
          int tok = ids_s[rl] >> 1;
          atomicAdd(&out[(size_t)tok * H_DIM + hcol0 + wn + n * 16 + ccol],
                    gw_s[rl] * acc[m][n][j]);
        }
      }
}

// ---------------- launch -----------------------------------------------------
extern "C" void kernel_launch(void* const* d_in, const int* in_sizes, int n_in,
                              void* d_out, int out_size, void* d_ws, size_t ws_size,
                              hipStream_t stream) {
  const float* x     = (const float*)d_in[0];
  const float* gatew = (const float*)d_in[1];
  const float* w1    = (const float*)d_in[2];
  const float* w3    = (const float*)d_in[3];
  const float* w2    = (const float*)d_in[4];
  float* out = (float*)d_out;

  char* ws = (char*)d_ws;
  int*   counts = (int*)ws;
  int*   ids    = (int*)(ws + 4096);
  float* gws    = (float*)(ws + 4096 + E_NUM * T_TOK * 4);

  const size_t WBYTES = (size_t)E_NUM * F_DIM * H_DIM * 2;  // 58,720,256
  unsigned short* xbf = (unsigned short*)(ws + (1ull << 20));
  unsigned short* w1b = (unsigned short*)(ws + (16ull << 20));
  unsigned short* w3b = (unsigned short*)(ws + (16ull << 20) + WBYTES);
  unsigned short* w2b = (unsigned short*)(ws + (16ull << 20) + 2 * WBYTES);
  unsigned short* Gf  = (unsigned short*)(ws + (16ull << 20) + 3 * WBYTES);
  // S2: 2 split-K partials = 67.1 MB; aliases w1b+w3b (dead after ffn1);
  // w2b (at +117.4MB) and Gf (at +176MB) stay clear.
  float* S2 = (float*)w1b;
  size_t required = (16ull << 20) + 4 * WBYTES;              // ~252 MB

  hipMemsetAsync(counts, 0, E_NUM * sizeof(int), stream);

  if (ws_size >= required) {
    const int n8 = (E_NUM * F_DIM * H_DIM) / 8;   // 3,670,016
    k_cvtgate<<<dim3(1024 + (n8 + 255) / 256), dim3(256), 0, stream>>>(
        x, gatew, counts, ids, gws, xbf, w1, w3, w2, w1b, w3b, w2b);
    k_ffn1_bf<<<dim3(F_DIM / 64, T_TOK / 128, E_NUM), dim3(512), 0, stream>>>(
        xbf, w1b, w3b, counts, ids, Gf);
    k_ffn2_bf<<<dim3(H_DIM / 64, T_TOK / 128, E_NUM * 2), dim3(256), 0, stream>>>(
        Gf, w2b, counts, ids, gws, S2);
    k_combine<<<dim3(1024), dim3(256), 0, stream>>>(
        S2, out, T_TOK * H_DIM / 4);
  } else {
    hipMemsetAsync(d_out, 0, (size_t)out_size * sizeof(float), stream);
    unsigned short* G = (unsigned short*)(ws + (1ull << 20));
    k_gate<<<dim3(T_TOK / 4), dim3(256), 0, stream>>>(
        x, gatew, counts, ids, gws, (unsigned short*)nullptr);
    k_ffn1_f32<<<dim3(F_DIM / 128, T_TOK / 128, E_NUM), dim3(256), 0, stream>>>(
        x, w1, w3, counts, ids, G);
    k_ffn2_f32<<<dim3(H_DIM / 128, T_TOK / 128, E_NUM), dim3(256), 0, stream>>>(
        G, w2, counts, ids, gws, out);
  }
}